// Round 7
// baseline (206.187 us; speedup 1.0000x reference)
//
#include <hip/hip_runtime.h>

#define N_ENT 100000
#define DIM 512
#define RANK 256
#define HROWS 256
#define MAXOBS 32
#define NBLK 1563          // ceil(100000/64)

typedef __attribute__((ext_vector_type(8))) short short8_t;
typedef __attribute__((ext_vector_type(4))) float f32x4;

__device__ __forceinline__ unsigned short f2bf(float f) {
  unsigned int x = __float_as_uint(f);
  x = x + 0x7fffu + ((x >> 16) & 1u);
  return (unsigned short)(x >> 16);
}

// ---- mask format handling (bool storage dtype is harness-dependent) ----
__device__ __forceinline__ int mask_mode(const int* flags) {
  int nz0 = flags[0], nz1 = flags[1], nz2 = flags[2], nz3 = flags[3];
  if (nz1 || (nz0 && (nz2 | nz3))) return 0;  // uint8
  if (nz0) return 1;                          // int32
  if (nz2 | nz3) return 2;                    // float32
  return 0;
}

__device__ __forceinline__ int mask_at(const void* mask, int idx, int mode) {
  if (mode == 0) return ((const unsigned char*)mask)[idx] != 0;
  if (mode == 1) return ((const int*)mask)[idx] != 0;
  return ((const float*)mask)[idx] != 0.0f;
}

__global__ void detect_mask_kernel(const unsigned char* __restrict__ mb, int* flags) {
  int t = threadIdx.x;
  int nz[4] = {0, 0, 0, 0};
  for (int j = 0; j < 32; ++j) {
    int idx = t * 32 + j;
    if (mb[idx]) nz[idx & 3] = 1;
  }
  for (int r = 0; r < 4; ++r)
    if (nz[r]) atomicOr(&flags[r], 1);
}

// ---- head extraction ----
__global__ void find_heads_kernel(const float* __restrict__ vec, int* counter, int* tmp) {
  int i = blockIdx.x * blockDim.x + threadIdx.x;
  if (i < N_ENT && vec[i] != 0.0f) {
    int p = atomicAdd(counter, 1);
    if (p < HROWS) tmp[p] = i;
  }
}

__global__ void sort_heads_kernel(const int* __restrict__ counter, const int* __restrict__ tmp,
                                  int* __restrict__ heads) {
  __shared__ int v[HROWS];
  int t = threadIdx.x;
  int cnt = *counter;
  if (cnt > HROWS) cnt = HROWS;
  v[t] = (t < cnt) ? tmp[t] : 0x7fffffff;
  __syncthreads();
  for (int k = 2; k <= HROWS; k <<= 1) {
    for (int j = k >> 1; j > 0; j >>= 1) {
      int ixj = t ^ j;
      if (ixj > t) {
        int a = v[t], b = v[ixj];
        bool up = ((t & k) == 0);
        if ((a > b) == up) { v[t] = b; v[ixj] = a; }
      }
      __syncthreads();
    }
  }
  heads[t] = (v[t] == 0x7fffffff) ? 0 : v[t];
}

// ---- query build (plain row-major bf16) ----
__global__ void build_q_kernel(const float* __restrict__ ent, const float* __restrict__ rel,
                               const int* __restrict__ heads, const int* __restrict__ rel_id,
                               unsigned short* __restrict__ q) {
  int b = blockIdx.x, k = threadIdx.x;
  int h = heads[b];
  const float* r = rel + (size_t)(*rel_id) * (2 * RANK);
  float re_h = ent[(size_t)h * DIM + k];
  float im_h = ent[(size_t)h * DIM + RANK + k];
  float re_r = r[k], im_r = r[RANK + k];
  q[(size_t)b * DIM + k]        = f2bf(re_h * re_r - im_h * im_r);
  q[(size_t)b * DIM + RANK + k] = f2bf(re_h * im_r + im_h * re_r);
}

// gate: retire tile kf's stage op. In-order vmem retirement; each body issues
// exactly ONE vmem op (the stage), bodies 12..15 issue none. No register-dest
// global loads exist in the loop, so these are the only vmem waits.
__device__ __forceinline__ void vm_gate(int kf) {
  if (kf <= 12)      asm volatile("s_waitcnt vmcnt(3)" ::: "memory");
  else if (kf == 13) asm volatile("s_waitcnt vmcnt(2)" ::: "memory");
  else if (kf == 14) asm volatile("s_waitcnt vmcnt(1)" ::: "memory");
  else               asm volatile("s_waitcnt vmcnt(0)" ::: "memory");
}

// ---- GEMM: out = exp(q(256x512) @ ent^T); per-block partial rowsums ----
// 1563 blocks x 512 thr (8 waves). Tile 256 rows x 64 cols, BK=32, 16 K-steps.
// A: ENTIRE per-wave A (2 frag x 16 steps = 128 VGPR) preloaded before loop.
// B: global_load_lds DMA, 6-buffer ring, 4 tiles in flight, counted vmcnt(3)
// gates + one s_barrier/step. Source-side XOR swizzle; f32 in LDS, cvt at read.
template <int MODE>
__global__ __launch_bounds__(512, 2) void gemm_scores_kernel(
    const float* __restrict__ ent, const unsigned short* __restrict__ q,
    float* __restrict__ out, float* __restrict__ partial) {
  __shared__ __align__(16) float Bs[6 * 2048];  // 6 bufs x (64 rows x 32 k f32)

  const int t = threadIdx.x;
  const int lane = t & 63;
  const int w = t >> 6;            // wave 0..7
  const int l15 = lane & 15;
  const int lk = lane >> 4;        // 0..3
  const int lk8 = lk * 8;
  const int e0 = blockIdx.x * 64;

  // staging: wave w stages rows [8w, 8w+8): chunk lane -> row 8w+(lane>>3),
  // LDS slot lane&7 holds global quad (lane&7)^((lane>>3)&7)  [XOR swizzle]
  const float* gsrc;
  {
    int ge = e0 + w * 8 + (lane >> 3);
    if (ge > N_ENT - 1) ge = N_ENT - 1;
    gsrc = ent + (size_t)ge * DIM + (((lane & 7) ^ ((lane >> 3) & 7)) << 2);
  }
  auto stage = [&](int buf, int kf2) {
    __builtin_amdgcn_global_load_lds(
        (const __attribute__((address_space(1))) void*)(gsrc + kf2 * 32),
        (__attribute__((address_space(3))) void*)((char*)Bs + buf * 8192 + w * 1024),
        16, 0, 0);
  };

  // ---- A preload: wave w owns rows [32w, 32w+32); all 16 k-steps in regs ----
  const unsigned short* ap0 = q + (size_t)(32 * w + l15) * DIM + lk8;
  const unsigned short* ap1 = ap0 + 16 * DIM;
  short8_t A0[16], A1[16];
#pragma unroll
  for (int kf = 0; kf < 16; ++kf) {
    A0[kf] = *reinterpret_cast<const short8_t*>(ap0 + kf * 32);
    A1[kf] = *reinterpret_cast<const short8_t*>(ap1 + kf * 32);
  }
  // ring prologue AFTER A loads: gate kf=0's vmcnt(3) retires A + stage0 exactly
  stage(0, 0); stage(1, 1); stage(2, 2); stage(3, 3);

  f32x4 acc[2][4] = {};

#pragma unroll
  for (int kf = 0; kf < 16; ++kf) {
    vm_gate(kf);                       // own-wave DMA for tile kf retired
    __builtin_amdgcn_s_barrier();      // all waves' tile-kf DMA retired
    if (kf < 12) stage((kf + 4) % 6, kf + 4);  // never a buffer in active read

    const char* bufp = (const char*)Bs + (kf % 6) * 8192;
    short8_t Bc[4];
#pragma unroll
    for (int fb = 0; fb < 4; ++fb) {
      const int r = fb * 16 + l15;
      const int x = r & 7;
      float4 f0 = *reinterpret_cast<const float4*>(bufp + r * 128 + (((2 * lk) ^ x) << 4));
      float4 f1 = *reinterpret_cast<const float4*>(bufp + r * 128 + (((2 * lk + 1) ^ x) << 4));
      unsigned int r0, r1, r2, r3;
      asm("v_cvt_pk_bf16_f32 %0, %1, %2" : "=v"(r0) : "v"(f0.x), "v"(f0.y));
      asm("v_cvt_pk_bf16_f32 %0, %1, %2" : "=v"(r1) : "v"(f0.z), "v"(f0.w));
      asm("v_cvt_pk_bf16_f32 %0, %1, %2" : "=v"(r2) : "v"(f1.x), "v"(f1.y));
      asm("v_cvt_pk_bf16_f32 %0, %1, %2" : "=v"(r3) : "v"(f1.z), "v"(f1.w));
      union { unsigned int u[4]; short8_t s8; } bf;
      bf.u[0] = r0; bf.u[1] = r1; bf.u[2] = r2; bf.u[3] = r3;
      Bc[fb] = bf.s8;
    }
#pragma unroll
    for (int fb = 0; fb < 4; ++fb) {
      acc[0][fb] = __builtin_amdgcn_mfma_f32_16x16x32_bf16(A0[kf], Bc[fb], acc[0][fb], 0, 0, 0);
      acc[1][fb] = __builtin_amdgcn_mfma_f32_16x16x32_bf16(A1[kf], Bc[fb], acc[1][fb], 0, 0, 0);
    }
  }

  // epilogue: C/D map col=lane&15, row=(lane>>4)*4+reg; store exp(s)
#pragma unroll
  for (int fr = 0; fr < 2; ++fr) {
#pragma unroll
    for (int j = 0; j < 4; ++j) {
      const int row = 32 * w + fr * 16 + lk * 4 + j;
      float psum = 0.0f;
#pragma unroll
      for (int fb = 0; fb < 4; ++fb) {
        const int col = e0 + fb * 16 + l15;
        if (col < N_ENT) {
          float p = __expf(acc[fr][fb][j]);  // |s| small: no max-subtraction
          out[(size_t)row * N_ENT + col] = p;
          psum += p;
        }
      }
      psum += __shfl_xor(psum, 1);
      psum += __shfl_xor(psum, 2);
      psum += __shfl_xor(psum, 4);
      psum += __shfl_xor(psum, 8);
      if (l15 == 0) {
        if (MODE == 0) partial[(size_t)blockIdx.x * HROWS + row] = psum;  // no atomics
        else atomicAdd(&partial[row], psum);
      }
    }
  }
}

// ---- fused: rowsum reduce + scaling -> factor[row] ----
__global__ void rowscale_kernel(const float* __restrict__ partial,
                                const float* __restrict__ pun,
                                const int* __restrict__ obs_idx, const void* __restrict__ mask,
                                const int* __restrict__ flags, float* __restrict__ factor) {
  __shared__ float red[256];
  __shared__ float rs_sh;
  const int row = blockIdx.x, t = threadIdx.x;
  float s = 0.0f;
  for (int k = t; k < NBLK; k += 256) s += partial[(size_t)k * HROWS + row];
  red[t] = s;
  __syncthreads();
  for (int m = 128; m > 0; m >>= 1) {
    if (t < m) red[t] += red[t + m];
    __syncthreads();
  }
  if (t == 0) rs_sh = red[0];
  __syncthreads();
  if (t < 32) {
    const int mode = mask_mode(flags);
    const int on = mask_at(mask, row * 32 + t, mode);
    float sume = 0.0f;
    float cntf = 0.0f;
    if (on) {
      sume = pun[(size_t)row * N_ENT + obs_idx[row * 32 + t]];
      cntf = 1.0f;
    }
#pragma unroll
    for (int m = 1; m < 32; m <<= 1) {
      sume += __shfl_xor(sume, m);
      cntf += __shfl_xor(cntf, m);
    }
    if (t == 0) {
      const float rs = rs_sh;
      float scaling = 1.0f;
      if (cntf > 0.0f) {
        float denom = fmaxf(sume / rs, 1e-30f);
        scaling = cntf / denom;
      }
      factor[row] = scaling / rs;
    }
  }
}

// ---- finalize: out = clamp(threshold(p_un * factor)) in place ----
__global__ __launch_bounds__(256) void finalize_kernel(float* __restrict__ out,
                                                       const float* __restrict__ factor,
                                                       const int* __restrict__ train) {
  int row = blockIdx.y;
  int i4 = blockIdx.x * blockDim.x + threadIdx.x;
  if (i4 >= N_ENT / 4) return;
  float f = factor[row];
  float hi = (*train) ? (1.0f - 0.001f) : 1.0f;
  float4* p = reinterpret_cast<float4*>(out + (size_t)row * N_ENT) + i4;
  float4 v = *p;
  float vals[4] = {v.x, v.y, v.z, v.w};
#pragma unroll
  for (int j = 0; j < 4; ++j) {
    float s = vals[j] * f;
    s = (s > 1e-4f) ? s : 0.0f;
    vals[j] = fminf(s, hi);
  }
  v.x = vals[0]; v.y = vals[1]; v.z = vals[2]; v.w = vals[3];
  *p = v;
}

// ---- observed positions -> 1.0 (train only) ----
__global__ void scatter_obs_kernel(float* __restrict__ out, const int* __restrict__ obs_idx,
                                   const void* __restrict__ mask, const int* __restrict__ flags,
                                   const int* __restrict__ train) {
  if (!(*train)) return;
  int t = blockIdx.x * blockDim.x + threadIdx.x;
  if (t >= HROWS * MAXOBS) return;
  int mode = mask_mode(flags);
  if (mask_at(mask, t, mode))
    out[(size_t)(t >> 5) * N_ENT + obs_idx[t]] = 1.0f;
}

extern "C" void kernel_launch(void* const* d_in, const int* in_sizes, int n_in,
                              void* d_out, int out_size, void* d_ws, size_t ws_size,
                              hipStream_t stream) {
  const float* ent      = (const float*)d_in[0];
  const float* rel      = (const float*)d_in[1];
  const float* head_vec = (const float*)d_in[2];
  const int* obs_idx    = (const int*)d_in[3];
  const void* obs_mask  = d_in[4];
  const int* rel_id     = (const int*)d_in[5];
  const int* train      = (const int*)d_in[7];
  float* out = (float*)d_out;

  char* ws = (char*)d_ws;
  int*   counter = (int*)(ws + 0);
  int*   flags   = (int*)(ws + 4);
  float* rowsum  = (float*)(ws + 64);
  float* factor  = (float*)(ws + 1088);
  int*   tmp     = (int*)(ws + 2112);
  int*   heads   = (int*)(ws + 3136);
  unsigned short* q = (unsigned short*)(ws + 4224);        // 256x512 bf16 = 256KB
  float* partial = (float*)(ws + 4224 + HROWS * DIM * 2);  // [1563][256] f32 = 1.6MB
  const size_t needed = 4224 + (size_t)HROWS * DIM * 2 + (size_t)NBLK * HROWS * 4;
  const bool big_ws = ws_size >= needed;

  hipMemsetAsync(ws, 0, 2112, stream);  // counter + flags + rowsum

  detect_mask_kernel<<<1, 256, 0, stream>>>((const unsigned char*)obs_mask, flags);
  find_heads_kernel<<<(N_ENT + 255) / 256, 256, 0, stream>>>(head_vec, counter, tmp);
  sort_heads_kernel<<<1, 256, 0, stream>>>(counter, tmp, heads);
  build_q_kernel<<<HROWS, 256, 0, stream>>>(ent, rel, heads, rel_id, q);
  if (big_ws) {
    gemm_scores_kernel<0><<<NBLK, 512, 0, stream>>>(ent, q, out, partial);
    rowscale_kernel<<<HROWS, 256, 0, stream>>>(partial, out, obs_idx, obs_mask, flags, factor);
  } else {
    gemm_scores_kernel<1><<<NBLK, 512, 0, stream>>>(ent, q, out, rowsum);
    rowscale_kernel<<<HROWS, 256, 0, stream>>>(rowsum, out, obs_idx, obs_mask, flags, factor);
  }
  finalize_kernel<<<dim3((N_ENT / 4 + 255) / 256, HROWS), 256, 0, stream>>>(out, factor, train);
  scatter_obs_kernel<<<(HROWS * MAXOBS + 255) / 256, 256, 0, stream>>>(out, obs_idx, obs_mask, flags, train);
}

// Round 8
// 164.191 us; speedup vs baseline: 1.2558x; 1.2558x over previous
//
#include <hip/hip_runtime.h>

#define N_ENT 100000
#define DIM 512
#define RANK 256
#define HROWS 256
#define MAXOBS 32
#define NBLK 1563          // ceil(100000/64)
#define BUFB 24576         // per ring buffer: B 8KB f32 + A 16KB bf16

typedef __attribute__((ext_vector_type(8))) short short8_t;
typedef __attribute__((ext_vector_type(4))) float f32x4;

__device__ __forceinline__ unsigned short f2bf(float f) {
  unsigned int x = __float_as_uint(f);
  x = x + 0x7fffu + ((x >> 16) & 1u);
  return (unsigned short)(x >> 16);
}

// ---- mask format handling (bool storage dtype is harness-dependent) ----
__device__ __forceinline__ int mask_mode(const int* flags) {
  int nz0 = flags[0], nz1 = flags[1], nz2 = flags[2], nz3 = flags[3];
  if (nz1 || (nz0 && (nz2 | nz3))) return 0;  // uint8
  if (nz0) return 1;                          // int32
  if (nz2 | nz3) return 2;                    // float32
  return 0;
}

__device__ __forceinline__ int mask_at(const void* mask, int idx, int mode) {
  if (mode == 0) return ((const unsigned char*)mask)[idx] != 0;
  if (mode == 1) return ((const int*)mask)[idx] != 0;
  return ((const float*)mask)[idx] != 0.0f;
}

__global__ void detect_mask_kernel(const unsigned char* __restrict__ mb, int* flags) {
  int t = threadIdx.x;
  int nz[4] = {0, 0, 0, 0};
  for (int j = 0; j < 32; ++j) {
    int idx = t * 32 + j;
    if (mb[idx]) nz[idx & 3] = 1;
  }
  for (int r = 0; r < 4; ++r)
    if (nz[r]) atomicOr(&flags[r], 1);
}

// ---- head extraction ----
__global__ void find_heads_kernel(const float* __restrict__ vec, int* counter, int* tmp) {
  int i = blockIdx.x * blockDim.x + threadIdx.x;
  if (i < N_ENT && vec[i] != 0.0f) {
    int p = atomicAdd(counter, 1);
    if (p < HROWS) tmp[p] = i;
  }
}

__global__ void sort_heads_kernel(const int* __restrict__ counter, const int* __restrict__ tmp,
                                  int* __restrict__ heads) {
  __shared__ int v[HROWS];
  int t = threadIdx.x;
  int cnt = *counter;
  if (cnt > HROWS) cnt = HROWS;
  v[t] = (t < cnt) ? tmp[t] : 0x7fffffff;
  __syncthreads();
  for (int k = 2; k <= HROWS; k <<= 1) {
    for (int j = k >> 1; j > 0; j >>= 1) {
      int ixj = t ^ j;
      if (ixj > t) {
        int a = v[t], b = v[ixj];
        bool up = ((t & k) == 0);
        if ((a > b) == up) { v[t] = b; v[ixj] = a; }
      }
      __syncthreads();
    }
  }
  heads[t] = (v[t] == 0x7fffffff) ? 0 : v[t];
}

// ---- query build (plain row-major bf16) ----
__global__ void build_q_kernel(const float* __restrict__ ent, const float* __restrict__ rel,
                               const int* __restrict__ heads, const int* __restrict__ rel_id,
                               unsigned short* __restrict__ q) {
  int b = blockIdx.x, k = threadIdx.x;
  int h = heads[b];
  const float* r = rel + (size_t)(*rel_id) * (2 * RANK);
  float re_h = ent[(size_t)h * DIM + k];
  float im_h = ent[(size_t)h * DIM + RANK + k];
  float re_r = r[k], im_r = r[RANK + k];
  q[(size_t)b * DIM + k]        = f2bf(re_h * re_r - im_h * im_r);
  q[(size_t)b * DIM + RANK + k] = f2bf(re_h * im_r + im_h * re_r);
}

// ---- GEMM: out = exp(q(256x512) @ ent^T); per-block partial rowsums ----
// 1563 blocks x 512 thr (8 waves). Tile 256 rows x 64 ents, BK=32, 16 K-steps.
// BOTH operands stream via global_load_lds DMA (A bf16 16KB + B f32 8KB per
// step, 3 instr/wave), 3-buffer ring, depth-2 prefetch, uniform vmcnt(3)
// gates + 1 raw s_barrier/step. ZERO register-dest global loads in the loop,
// so no compiler-inserted vmem wait can collapse the ring (R6/R7 bug).
// Both tiles source-side XOR-swizzled -> uniform 8-lanes-per-16B-quad reads.
template <int MODE>
__global__ __launch_bounds__(512, 2) void gemm_scores_kernel(
    const float* __restrict__ ent, const unsigned short* __restrict__ q,
    float* __restrict__ out, float* __restrict__ partial) {
  __shared__ __align__(16) char Bs[3 * BUFB];

  const int t = threadIdx.x;
  const int lane = t & 63;
  const int w = t >> 6;            // wave 0..7
  const int l15 = lane & 15;
  const int lk = lane >> 4;        // 0..3
  const int e0 = blockIdx.x * 64;

  // B stage src: wave w rows [8w,8w+8) of 64 ents; quad (lane&7)^((lane>>3)&7)
  const float* gsB;
  {
    int ge = e0 + w * 8 + (lane >> 3);
    if (ge > N_ENT - 1) ge = N_ENT - 1;
    gsB = ent + (size_t)ge * DIM + (((lane & 7) ^ ((lane >> 3) & 7)) << 2);
  }
  // A stage src: wave w stages its OWN q-rows [32w,32w+32); 2 instr (j=0,1);
  // 64B row = 4 chunks; LDS slot c holds global chunk c^((row>>1)&3)
  const unsigned short* gsA[2];
#pragma unroll
  for (int j = 0; j < 2; ++j) {
    const int row = w * 32 + j * 16 + (lane >> 2);
    gsA[j] = q + (size_t)row * DIM + (((lane & 3) ^ ((row >> 1) & 3)) << 3);
  }
  auto stage = [&](int buf, int kf) {
    char* base = Bs + buf * BUFB;
    __builtin_amdgcn_global_load_lds(
        (const __attribute__((address_space(1))) void*)(gsB + kf * 32),
        (__attribute__((address_space(3))) void*)(base + w * 1024), 16, 0, 0);
    __builtin_amdgcn_global_load_lds(
        (const __attribute__((address_space(1))) void*)(gsA[0] + kf * 32),
        (__attribute__((address_space(3))) void*)(base + 8192 + w * 2048), 16, 0, 0);
    __builtin_amdgcn_global_load_lds(
        (const __attribute__((address_space(1))) void*)(gsA[1] + kf * 32),
        (__attribute__((address_space(3))) void*)(base + 8192 + w * 2048 + 1024), 16, 0, 0);
  };

  stage(0, 0);
  stage(1, 1);

  f32x4 acc[2][4] = {};

#pragma unroll
  for (int kf = 0; kf < 16; ++kf) {
    // gate: stages kf+1 (3 ops) may remain outstanding; stage kf retired.
    if (kf < 15) asm volatile("s_waitcnt vmcnt(3)" ::: "memory");
    else         asm volatile("s_waitcnt vmcnt(0)" ::: "memory");
    __builtin_amdgcn_s_barrier();          // all waves' tile-kf DMA retired
    if (kf < 14) stage((kf + 2) % 3, kf + 2);  // buf (kf-1)%3: reads done

    const char* bufp = Bs + (kf % 3) * BUFB;
    // B: 4 col-frags, f32 -> bf16 via cvt_pk
    short8_t Bc[4];
#pragma unroll
    for (int fb = 0; fb < 4; ++fb) {
      const int r = fb * 16 + l15;
      const int x = r & 7;
      float4 f0 = *reinterpret_cast<const float4*>(bufp + r * 128 + (((2 * lk) ^ x) << 4));
      float4 f1 = *reinterpret_cast<const float4*>(bufp + r * 128 + (((2 * lk + 1) ^ x) << 4));
      unsigned int r0, r1, r2, r3;
      asm("v_cvt_pk_bf16_f32 %0, %1, %2" : "=v"(r0) : "v"(f0.x), "v"(f0.y));
      asm("v_cvt_pk_bf16_f32 %0, %1, %2" : "=v"(r1) : "v"(f0.z), "v"(f0.w));
      asm("v_cvt_pk_bf16_f32 %0, %1, %2" : "=v"(r2) : "v"(f1.x), "v"(f1.y));
      asm("v_cvt_pk_bf16_f32 %0, %1, %2" : "=v"(r3) : "v"(f1.z), "v"(f1.w));
      union { unsigned int u[4]; short8_t s8; } bf;
      bf.u[0] = r0; bf.u[1] = r1; bf.u[2] = r2; bf.u[3] = r3;
      Bc[fb] = bf.s8;
    }
    // A: 2 row-frags from this wave's staged rows
    short8_t Af[2];
#pragma unroll
    for (int fr = 0; fr < 2; ++fr) {
      const int r = w * 32 + fr * 16 + l15;
      const int s = (r >> 1) & 3;
      Af[fr] = *reinterpret_cast<const short8_t*>(bufp + 8192 + r * 64 + ((lk ^ s) << 4));
    }
#pragma unroll
    for (int fb = 0; fb < 4; ++fb) {
      acc[0][fb] = __builtin_amdgcn_mfma_f32_16x16x32_bf16(Af[0], Bc[fb], acc[0][fb], 0, 0, 0);
      acc[1][fb] = __builtin_amdgcn_mfma_f32_16x16x32_bf16(Af[1], Bc[fb], acc[1][fb], 0, 0, 0);
    }
  }

  // epilogue: C/D map col=lane&15, row=(lane>>4)*4+reg; store exp(s)
#pragma unroll
  for (int fr = 0; fr < 2; ++fr) {
#pragma unroll
    for (int j = 0; j < 4; ++j) {
      const int row = 32 * w + fr * 16 + lk * 4 + j;
      float psum = 0.0f;
#pragma unroll
      for (int fb = 0; fb < 4; ++fb) {
        const int col = e0 + fb * 16 + l15;
        if (col < N_ENT) {
          float p = __expf(acc[fr][fb][j]);  // |s| small: no max-subtraction
          out[(size_t)row * N_ENT + col] = p;
          psum += p;
        }
      }
      psum += __shfl_xor(psum, 1);
      psum += __shfl_xor(psum, 2);
      psum += __shfl_xor(psum, 4);
      psum += __shfl_xor(psum, 8);
      if (l15 == 0) {
        if (MODE == 0) partial[(size_t)blockIdx.x * HROWS + row] = psum;  // no atomics
        else atomicAdd(&partial[row], psum);
      }
    }
  }
}

// ---- fused: rowsum reduce + scaling -> factor[row] ----
__global__ void rowscale_kernel(const float* __restrict__ partial,
                                const float* __restrict__ pun,
                                const int* __restrict__ obs_idx, const void* __restrict__ mask,
                                const int* __restrict__ flags, float* __restrict__ factor) {
  __shared__ float red[256];
  __shared__ float rs_sh;
  const int row = blockIdx.x, t = threadIdx.x;
  float s = 0.0f;
  for (int k = t; k < NBLK; k += 256) s += partial[(size_t)k * HROWS + row];
  red[t] = s;
  __syncthreads();
  for (int m = 128; m > 0; m >>= 1) {
    if (t < m) red[t] += red[t + m];
    __syncthreads();
  }
  if (t == 0) rs_sh = red[0];
  __syncthreads();
  if (t < 32) {
    const int mode = mask_mode(flags);
    const int on = mask_at(mask, row * 32 + t, mode);
    float sume = 0.0f;
    float cntf = 0.0f;
    if (on) {
      sume = pun[(size_t)row * N_ENT + obs_idx[row * 32 + t]];
      cntf = 1.0f;
    }
#pragma unroll
    for (int m = 1; m < 32; m <<= 1) {
      sume += __shfl_xor(sume, m);
      cntf += __shfl_xor(cntf, m);
    }
    if (t == 0) {
      const float rs = rs_sh;
      float scaling = 1.0f;
      if (cntf > 0.0f) {
        float denom = fmaxf(sume / rs, 1e-30f);
        scaling = cntf / denom;
      }
      factor[row] = scaling / rs;
    }
  }
}

// ---- finalize: out = clamp(threshold(p_un * factor)) in place ----
__global__ __launch_bounds__(256) void finalize_kernel(float* __restrict__ out,
                                                       const float* __restrict__ factor,
                                                       const int* __restrict__ train) {
  int row = blockIdx.y;
  int i4 = blockIdx.x * blockDim.x + threadIdx.x;
  if (i4 >= N_ENT / 4) return;
  float f = factor[row];
  float hi = (*train) ? (1.0f - 0.001f) : 1.0f;
  float4* p = reinterpret_cast<float4*>(out + (size_t)row * N_ENT) + i4;
  float4 v = *p;
  float vals[4] = {v.x, v.y, v.z, v.w};
#pragma unroll
  for (int j = 0; j < 4; ++j) {
    float s = vals[j] * f;
    s = (s > 1e-4f) ? s : 0.0f;
    vals[j] = fminf(s, hi);
  }
  v.x = vals[0]; v.y = vals[1]; v.z = vals[2]; v.w = vals[3];
  *p = v;
}

// ---- observed positions -> 1.0 (train only) ----
__global__ void scatter_obs_kernel(float* __restrict__ out, const int* __restrict__ obs_idx,
                                   const void* __restrict__ mask, const int* __restrict__ flags,
                                   const int* __restrict__ train) {
  if (!(*train)) return;
  int t = blockIdx.x * blockDim.x + threadIdx.x;
  if (t >= HROWS * MAXOBS) return;
  int mode = mask_mode(flags);
  if (mask_at(mask, t, mode))
    out[(size_t)(t >> 5) * N_ENT + obs_idx[t]] = 1.0f;
}

extern "C" void kernel_launch(void* const* d_in, const int* in_sizes, int n_in,
                              void* d_out, int out_size, void* d_ws, size_t ws_size,
                              hipStream_t stream) {
  const float* ent      = (const float*)d_in[0];
  const float* rel      = (const float*)d_in[1];
  const float* head_vec = (const float*)d_in[2];
  const int* obs_idx    = (const int*)d_in[3];
  const void* obs_mask  = d_in[4];
  const int* rel_id     = (const int*)d_in[5];
  const int* train      = (const int*)d_in[7];
  float* out = (float*)d_out;

  char* ws = (char*)d_ws;
  int*   counter = (int*)(ws + 0);
  int*   flags   = (int*)(ws + 4);
  float* rowsum  = (float*)(ws + 64);
  float* factor  = (float*)(ws + 1088);
  int*   tmp     = (int*)(ws + 2112);
  int*   heads   = (int*)(ws + 3136);
  unsigned short* q = (unsigned short*)(ws + 4224);        // 256x512 bf16 = 256KB
  float* partial = (float*)(ws + 4224 + HROWS * DIM * 2);  // [1563][256] f32 = 1.6MB
  const size_t needed = 4224 + (size_t)HROWS * DIM * 2 + (size_t)NBLK * HROWS * 4;
  const bool big_ws = ws_size >= needed;

  hipMemsetAsync(ws, 0, 2112, stream);  // counter + flags + rowsum

  detect_mask_kernel<<<1, 256, 0, stream>>>((const unsigned char*)obs_mask, flags);
  find_heads_kernel<<<(N_ENT + 255) / 256, 256, 0, stream>>>(head_vec, counter, tmp);
  sort_heads_kernel<<<1, 256, 0, stream>>>(counter, tmp, heads);
  build_q_kernel<<<HROWS, 256, 0, stream>>>(ent, rel, heads, rel_id, q);
  if (big_ws) {
    gemm_scores_kernel<0><<<NBLK, 512, 0, stream>>>(ent, q, out, partial);
    rowscale_kernel<<<HROWS, 256, 0, stream>>>(partial, out, obs_idx, obs_mask, flags, factor);
  } else {
    gemm_scores_kernel<1><<<NBLK, 512, 0, stream>>>(ent, q, out, rowsum);
    rowscale_kernel<<<HROWS, 256, 0, stream>>>(rowsum, out, obs_idx, obs_mask, flags, factor);
  }
  finalize_kernel<<<dim3((N_ENT / 4 + 255) / 256, HROWS), 256, 0, stream>>>(out, factor, train);
  scatter_obs_kernel<<<(HROWS * MAXOBS + 255) / 256, 256, 0, stream>>>(out, obs_idx, obs_mask, flags, train);
}